// Round 1
// baseline (46.666 us; speedup 1.0000x reference)
//
#include <hip/hip_runtime.h>

#define EPSF 1e-8f

constexpr int B   = 16;
constexpr int C   = 32;
constexpr int O   = 32;
constexpr int HW  = 196;   // 14*14
constexpr int S9  = 9;     // s_in
constexpr int T9  = 9;     // s_out
constexpr int CH  = 28;    // hw chunk (196 = 7*28)
constexpr int NCH = HW / CH;
constexpr int PART_N = C * O * B * T9;  // 147456 floats per moment array

// ---------------------------------------------------------------------------
// Kernel A: per (c,o) block, stream T slice, accumulate S1/S2 partials.
// thread tid: b = tid>>4 (0..15), hwl = tid&15 (0..15)
// ---------------------------------------------------------------------------
__global__ __launch_bounds__(256) void caps_main(
    const float* __restrict__ x,   // [B][C][HW][9]
    const float* __restrict__ p,   // [B][C][HW]
    const float* __restrict__ T,   // [C][O][HW][9][9]
    float* __restrict__ part1,     // [C][O][B][9]
    float* __restrict__ part2)     // [C][O][B][9]
{
    const int c   = blockIdx.x;
    const int o   = blockIdx.y;
    const int tid = threadIdx.x;
    const int b   = tid >> 4;
    const int hwl = tid & 15;

    // padded LDS: [CH][9 t][3 float4]  (row = 12 floats, 16B-aligned)
    __shared__ float4 ts4[CH * T9 * 3];   // 756 float4 = 12096 B

    const float* Tb = T + (size_t)(c * O + o) * (HW * 81);
    const float* xb = x + (size_t)b * (C * HW * S9) + (size_t)c * (HW * S9);
    const float* pb = p + (size_t)b * (C * HW) + (size_t)c * HW;

    float acc1[T9], acc2[T9];
#pragma unroll
    for (int t = 0; t < T9; ++t) { acc1[t] = 0.f; acc2[t] = 0.f; }

    for (int k = 0; k < NCH; ++k) {
        const int hw0 = k * CH;
        if (k) __syncthreads();   // protect LDS reuse

        // stage 252 rows (hw_local, t) of 9 floats each, scaled by 0.1
        if (tid < CH * T9) {
            const float* g = Tb + (size_t)hw0 * 81 + (size_t)tid * 9;
            float g0 = g[0], g1 = g[1], g2 = g[2], g3 = g[3];
            float g4 = g[4], g5 = g[5], g6 = g[6], g7 = g[7];
            float g8 = g[8];
            float4 A = make_float4(g0 * 0.1f, g1 * 0.1f, g2 * 0.1f, g3 * 0.1f);
            float4 Bv = make_float4(g4 * 0.1f, g5 * 0.1f, g6 * 0.1f, g7 * 0.1f);
            ts4[tid * 3 + 0] = A;
            ts4[tid * 3 + 1] = Bv;
            ts4[tid * 3 + 2] = make_float4(g8 * 0.1f, 0.f, 0.f, 0.f);
        }
        __syncthreads();

#pragma unroll
        for (int rep = 0; rep < 2; ++rep) {
            const int hwc = hwl + rep * 16;
            if (hwc < CH) {
                const int hw = hw0 + hwc;
                const float* xg = xb + (size_t)hw * 9;
                float xr0 = xg[0], xr1 = xg[1], xr2 = xg[2], xr3 = xg[3];
                float xr4 = xg[4], xr5 = xg[5], xr6 = xg[6], xr7 = xg[7];
                float xr8 = xg[8];
                float pf = pb[hw];
#pragma unroll
                for (int t = 0; t < T9; ++t) {
                    float4 ta = ts4[hwc * 27 + t * 3 + 0];
                    float4 tb = ts4[hwc * 27 + t * 3 + 1];
                    float t8  = ts4[hwc * 27 + t * 3 + 2].x;
                    float pr = ta.x * xr0 + ta.y * xr1 + ta.z * xr2 + ta.w * xr3
                             + tb.x * xr4 + tb.y * xr5 + tb.z * xr6 + tb.w * xr7
                             + t8 * xr8;
                    acc1[t] += pf * pr;
                    acc2[t] += pf * pr * pr;
                }
            }
        }
    }

    // reduce across the 16 hw-lanes (contiguous within a wave)
#pragma unroll
    for (int t = 0; t < T9; ++t) {
#pragma unroll
        for (int m = 1; m < 16; m <<= 1) {
            acc1[t] += __shfl_xor(acc1[t], m, 64);
            acc2[t] += __shfl_xor(acc2[t], m, 64);
        }
    }
    if (hwl == 0) {
        float* p1 = part1 + ((size_t)(c * O + o) * B + b) * T9;
        float* p2 = part2 + ((size_t)(c * O + o) * B + b) * T9;
#pragma unroll
        for (int t = 0; t < T9; ++t) { p1[t] = acc1[t]; p2[t] = acc2[t]; }
    }
}

// ---------------------------------------------------------------------------
// Kernel B: per-b finalize. psum, reduce partials over c, caps/var/vs/p_upd.
// ---------------------------------------------------------------------------
__global__ __launch_bounds__(256) void caps_final(
    const float* __restrict__ p,      // [B][C][HW]
    const float* __restrict__ part1,
    const float* __restrict__ part2,
    float* __restrict__ out)          // caps [B][O][9] then p_updated [B][O]
{
    const int b   = blockIdx.x;
    const int tid = threadIdx.x;

    __shared__ float vlds[O * T9];   // 288
    __shared__ float red[4];
    __shared__ float s_psum;

    // psum[b] = sum over 6272 contiguous floats
    const float* pb = p + (size_t)b * (C * HW);
    float a = 0.f;
    for (int i = tid; i < C * HW; i += 256) a += pb[i];
#pragma unroll
    for (int m = 1; m < 64; m <<= 1) a += __shfl_xor(a, m, 64);
    if ((tid & 63) == 0) red[tid >> 6] = a;
    __syncthreads();
    if (tid == 0) s_psum = (red[0] + red[1]) + (red[2] + red[3]);
    __syncthreads();
    const float psum  = s_psum;
    const float denom = psum + EPSF;

    for (int e = tid; e < O * T9; e += 256) {
        const int o = e / T9, t = e % T9;
        float s1 = 0.f, s2 = 0.f;
        for (int c = 0; c < C; ++c) {
            const size_t idx = ((size_t)(c * O + o) * B + b) * T9 + t;
            s1 += part1[idx];
            s2 += part2[idx];
        }
        const float caps = s1 / denom;
        out[(size_t)(b * O + o) * T9 + t] = caps;
        const float var = (s2 - 2.f * caps * s1 + caps * caps * psum) / denom;
        vlds[e] = var;
    }
    __syncthreads();

    if (tid < O) {
        float vs = 0.f;
#pragma unroll
        for (int t = 0; t < T9; ++t) vs += vlds[tid * T9 + t];
        float mx = vs;
#pragma unroll
        for (int msk = 1; msk < 32; msk <<= 1) mx = fmaxf(mx, __shfl_xor(mx, msk, 64));
        out[(size_t)B * O * T9 + b * O + tid] = 1.f - vs / (mx + EPSF);
    }
}

extern "C" void kernel_launch(void* const* d_in, const int* in_sizes, int n_in,
                              void* d_out, int out_size, void* d_ws, size_t ws_size,
                              hipStream_t stream)
{
    (void)in_sizes; (void)n_in; (void)out_size; (void)ws_size;
    const float* x = (const float*)d_in[0];   // (16,32,14,14,9)
    const float* p = (const float*)d_in[1];   // (16,32,14,14)
    // d_in[2] = epoch (unused)
    const float* T = (const float*)d_in[3];   // (1,32,32,14,14,9,9)
    float* out = (float*)d_out;

    float* part1 = (float*)d_ws;
    float* part2 = part1 + PART_N;

    dim3 gridA(C, O);
    caps_main<<<gridA, 256, 0, stream>>>(x, p, T, part1, part2);
    caps_final<<<B, 256, 0, stream>>>(p, part1, part2, out);
}